// Round 5
// baseline (588.892 us; speedup 1.0000x reference)
//
#include <hip/hip_runtime.h>
#include <cstdint>
#include <cstddef>

// VQ-VAE vector quantizer forward, MI355X.
// B=65536 rows, K=4096 codes, D=256.
// Outputs (flat float32): z_q_st[B*D] | vq_loss | perplexity | indices[B] | diversity_loss

#define NROWS     65536
#define NCODES    4096
#define DDIM      256
#define CAND_CAP  24
#define MARGIN    0.5f
#define SKIP_THR  17.0f

typedef _Float16 half8 __attribute__((ext_vector_type(8)));
typedef _Float16 half4 __attribute__((ext_vector_type(4)));
typedef float    f32x4 __attribute__((ext_vector_type(4)));

// ---- workspace layout (bytes) ----
#define WS_CANDCNT  0u          // 65536*4   = 262144   (zeroed)
#define WS_BINCNT   262144u     // 4096*4    = 16384    (zeroed)
#define WS_ZERO_END 278528u
#define WS_SPART    278528u     // 512*4096*4 = 8388608 (fully written by sweep)
#define WS_EF16     8667136u    // 4096*256*2 = 2097152
#define WS_EE       10764288u   // 4096*4     = 16384
#define WS_ROWD     10780672u   // 65536*4    = 262144
#define WS_CANDIDX  11042816u   // 65536*24*4 = 6291456 (aliased as tm[4096] dbl after refine)
#define WS_TE       17334272u   // 4096*8     = 32768
#define WS_TP       17367040u   // 4096*8     = 32768
#define WS_END      17399808u

__device__ __forceinline__ void gload_lds16(const void* g, void* lds) {
    __builtin_amdgcn_global_load_lds(
        (const __attribute__((address_space(1))) unsigned int*)g,
        (__attribute__((address_space(3))) unsigned int*)lds, 16, 0, 0);
}

// ---------------- prep (embedding only): fp32 -> fp16 copy + row norms ----------------
__global__ __launch_bounds__(256)
void prep_kernel(const float* __restrict__ src, _Float16* __restrict__ dst,
                 float* __restrict__ norms)
{
    const int tid = threadIdx.x;
    const int w = tid >> 6, l = tid & 63;
    const int row = blockIdx.x * 4 + w;
    const float4 v = *(const float4*)(src + (size_t)row * DDIM + l * 4);
    half4 h;
    h[0] = (_Float16)v.x; h[1] = (_Float16)v.y;
    h[2] = (_Float16)v.z; h[3] = (_Float16)v.w;
    *(half4*)(dst + (size_t)row * DDIM + l * 4) = h;
    double s = (double)v.x * v.x + (double)v.y * v.y
             + (double)v.z * v.z + (double)v.w * v.w;
#pragma unroll
    for (int off = 1; off < 64; off <<= 1) s += __shfl_xor(s, off, 64);
    if (l == 0) norms[row] = (float)s;
}

// ---------------- fused two-phase distance sweep, double-buffered ----------------
// Block: 128 rows x all 4096 codes. 4 waves = 2 M-groups (wm: 64 rows, fr=0..3)
//        x 2 N-groups (wn: 32 of the 64 tile codes, cf=0..1).
// A fragments (fp16, converted from f32 z in-register) live in VGPRs throughout.
// B: 64-code x K=256 sub-tiles, 2 x 32 KB LDS double-buffer, stored FRAGMENT-MAJOR:
//   slot (ksl*4+cfg)*1024 + lane*16  <- global row cfg*16+(l&15), kbytes ksl*64+(l>>4)*16
// staged via global_load_lds (linear LDS dest = lane*16; per-lane global source does the
// permute).  Reads are lane-linear ds_read_b128 -> zero bank conflicts by construction.
// Sweep runs on shifted distances d' = ||e||^2 - 2 z.e (row-shift invariant).
// Phase 0 (steps 0..63): exact online (m, Z) with defer-rescale + skip-far exp.
// Phase 1 (steps 64..127): identical d'; soft partials into LDS Sl; candidates.
__global__ __launch_bounds__(256, 2)
void sweep_fused_kernel(const float* __restrict__ z, const _Float16* __restrict__ ef,
                        const float* __restrict__ ee, float* __restrict__ Spart,
                        int* __restrict__ cand_cnt, int* __restrict__ cand_idx)
{
    __shared__ _Float16 Bl[2][64 * 256];   // 2 x 32 KB, fragment-major
    __shared__ float Sl[NCODES];           // 16 KB soft accumulator

    const int tid = threadIdx.x;
    const int w = tid >> 6, l = tid & 63;
    const int wm = w & 1, wn = w >> 1;
    const int lg = l >> 4, lc = l & 15;
    const int row0 = blockIdx.x * 128;

    // A fragments: row = row0 + wm*64 + fr*16 + lc, k = ksl*32 + lg*8 .. +8 (f32 -> f16)
    half8 af[4][8];
#pragma unroll
    for (int fr = 0; fr < 4; ++fr)
#pragma unroll
    for (int ksl = 0; ksl < 8; ++ksl) {
        const float* zp = z + (size_t)(row0 + wm * 64 + fr * 16 + lc) * DDIM + ksl * 32 + lg * 8;
        const float4 v0 = *(const float4*)zp;
        const float4 v1 = *(const float4*)(zp + 4);
        half8 h;
        h[0] = (_Float16)v0.x; h[1] = (_Float16)v0.y; h[2] = (_Float16)v0.z; h[3] = (_Float16)v0.w;
        h[4] = (_Float16)v1.x; h[5] = (_Float16)v1.y; h[6] = (_Float16)v1.z; h[7] = (_Float16)v1.w;
        af[fr][ksl] = h;
    }

    for (int i = tid; i < NCODES; i += 256) Sl[i] = 0.0f;

    // staging: instr it_g = w*8+it covers (ksl=it_g>>2, cfg=it_g&3); lane l fetches
    // global row cfg*16+lc, kbytes ksl*64+lg*16 -> LDS slot it_g*1024 + l*16 (linear).
    int soff[8];
#pragma unroll
    for (int it = 0; it < 8; ++it) {
        const int it_g = w * 8 + it;
        const int ksl = it_g >> 2, cfg = it_g & 3;
        soff[it] = (cfg * 16 + lc) * 512 + ksl * 64 + lg * 16;
    }
    const char* efb = (const char*)ef;
    char* blb = (char*)&Bl[0][0];

    float pm[16], pZ[16];
#pragma unroll
    for (int i = 0; i < 16; ++i) { pm[i] = 1e30f; pZ[i] = 0.0f; }

    // prologue: stage tile nt=0 into buffer 0
#pragma unroll
    for (int it = 0; it < 8; ++it)
        gload_lds16(efb + soff[it], blb + (w * 8 + it) * 1024);
    __syncthreads();

    for (int s = 0; s < 128; ++s) {
        const int cur = s & 1;
        const int nt = s & 63;

        if (s < 127) {                      // stage next sub-tile into other buffer
            const int nnt = (s + 1) & 63;
            const char* src = efb + ((size_t)nnt << 15);
            char* dst = blb + (cur ^ 1) * 32768;
#pragma unroll
            for (int it = 0; it < 8; ++it)
                gload_lds16(src + soff[it], dst + (w * 8 + it) * 1024);
        }

        float eev[2];
#pragma unroll
        for (int cf = 0; cf < 2; ++cf)
            eev[cf] = ee[nt * 64 + (wn * 2 + cf) * 16 + lc];

        f32x4 acc[4][2];
#pragma unroll
        for (int fr = 0; fr < 4; ++fr) {
            acc[fr][0] = (f32x4){0.f, 0.f, 0.f, 0.f};
            acc[fr][1] = (f32x4){0.f, 0.f, 0.f, 0.f};
        }

        // lane-linear B reads (conflict-free), immediate offsets
        const char* bb = blb + cur * 32768 + (l << 4) + wn * 2048;
#pragma unroll
        for (int ksl = 0; ksl < 8; ++ksl) {
            const half8 b0 = *(const half8*)(bb + (ksl * 4 + 0) * 1024);
            const half8 b1 = *(const half8*)(bb + (ksl * 4 + 1) * 1024);
#pragma unroll
            for (int fr = 0; fr < 4; ++fr) {
                acc[fr][0] = __builtin_amdgcn_mfma_f32_16x16x32_f16(af[fr][ksl], b0, acc[fr][0], 0, 0, 0);
                acc[fr][1] = __builtin_amdgcn_mfma_f32_16x16x32_f16(af[fr][ksl], b1, acc[fr][1], 0, 0, 0);
            }
        }

        if (s < 64) {
            // phase 0: exact online (m, Z); rescale only on min-improve; skip far groups
#pragma unroll
            for (int fr = 0; fr < 4; ++fr)
#pragma unroll
            for (int reg = 0; reg < 4; ++reg) {
                const int ri = fr * 4 + reg;
                const float d0 = fmaf(-2.0f, acc[fr][0][reg], eev[0]);
                const float d1 = fmaf(-2.0f, acc[fr][1][reg], eev[1]);
                const float mloc = fminf(d0, d1);
                float m = pm[ri];
                if (mloc < m + SKIP_THR) {   // dropped terms < e^-17, Z >= 1
                    if (mloc < m) { pZ[ri] *= __expf(mloc - m); m = mloc; pm[ri] = m; }
                    pZ[ri] += __expf(m - d0) + __expf(m - d1);
                }
            }
        } else {
            // phase 1: d' bitwise identical to phase 0 (same regs, same ops)
            float sp[2] = {0.f, 0.f};
#pragma unroll
            for (int fr = 0; fr < 4; ++fr)
#pragma unroll
            for (int reg = 0; reg < 4; ++reg) {
                const int ri = fr * 4 + reg;
                const float m = pm[ri], iz = pZ[ri];   // pZ holds 1/Z in phase 1
#pragma unroll
                for (int cf = 0; cf < 2; ++cf) {
                    const float d = fmaf(-2.0f, acc[fr][cf][reg], eev[cf]);
                    if (d <= m + SKIP_THR) {
                        sp[cf] += __expf(m - d) * iz;
                        if (d <= m + MARGIN) {   // m = exact min of phase-0 d' for this row
                            const int rg_ = row0 + wm * 64 + fr * 16 + lg * 4 + reg;
                            const int slot = atomicAdd(&cand_cnt[rg_], 1);
                            if (slot < CAND_CAP)
                                cand_idx[(size_t)rg_ * CAND_CAP + slot]
                                    = nt * 64 + (wn * 2 + cf) * 16 + lc;
                        }
                    }
                }
            }
#pragma unroll
            for (int cf = 0; cf < 2; ++cf) {   // sum across lg, then LDS accumulate
                float v = sp[cf];
                v += __shfl_xor(v, 16, 64);
                v += __shfl_xor(v, 32, 64);
                if (l < 16) atomicAdd(&Sl[nt * 64 + (wn * 2 + cf) * 16 + l], v);
            }
        }

        if (s == 63) {
            // phase boundary: merge (m,Z) across the 16 lanes (lc) sharing each row; pZ := 1/Z
#pragma unroll
            for (int ri = 0; ri < 16; ++ri) {
                float m = pm[ri], Zv = pZ[ri];
#pragma unroll
                for (int off = 1; off < 16; off <<= 1) {
                    const float mo = __shfl_xor(m, off, 64);
                    const float Zo = __shfl_xor(Zv, off, 64);
                    const float mn = fminf(m, mo);
                    Zv = Zv * __expf(mn - m) + Zo * __expf(mn - mo);
                    m = mn;
                }
                pm[ri] = m;
                pZ[ri] = 1.0f / Zv;
            }
        }

        __syncthreads();   // drains stage(s+1) loads (issued a full compute phase ago)
    }

    for (int i = tid; i < NCODES; i += 256)
        Spart[(size_t)blockIdx.x * NCODES + i] = Sl[i];
}

// ---------------- refine: exact fp64 argmin over candidates ----------------
__global__ __launch_bounds__(256)
void refine_kernel(const float* __restrict__ z, const float* __restrict__ emb,
                   const int* __restrict__ cand_cnt, const int* __restrict__ cand_idx,
                   float* __restrict__ out_zq, float* __restrict__ out_idx,
                   unsigned int* __restrict__ bincnt, float* __restrict__ rowD)
{
    const int tid = threadIdx.x;
    const int w = tid >> 6, l = tid & 63;
    const int row = blockIdx.x * 4 + w;
    const float4 zv = *(const float4*)(z + (size_t)row * DDIM + l * 4);
    const double z0 = zv.x, z1 = zv.y, z2 = zv.z, z3 = zv.w;
    const int craw = cand_cnt[row];
    const int cnt = craw < 1 ? 1 : (craw > CAND_CAP ? CAND_CAP : craw);
    double dmin = 1e300; int kmin = 0;
    for (int c = 0; c < cnt; ++c) {
        int k = (craw < 1) ? 0 : cand_idx[(size_t)row * CAND_CAP + c];
        k &= (NCODES - 1);
        const float4 ev = *(const float4*)(emb + (size_t)k * DDIM + l * 4);
        const double t0 = z0 - ev.x, t1 = z1 - ev.y, t2 = z2 - ev.z, t3 = z3 - ev.w;
        double s = t0 * t0 + t1 * t1 + t2 * t2 + t3 * t3;
#pragma unroll
        for (int off = 1; off < 64; off <<= 1) s += __shfl_xor(s, off, 64);
        if (s < dmin || (s == dmin && k < kmin)) { dmin = s; kmin = k; }
    }
    const float4 bv = *(const float4*)(emb + (size_t)kmin * DDIM + l * 4);
    *(float4*)(out_zq + (size_t)row * DDIM + l * 4) = bv;   // z + sg(zq - z) == zq
    if (l == 0) {
        out_idx[row] = (float)kmin;
        atomicAdd(&bincnt[kmin], 1u);
        rowD[row] = (float)dmin;                             // dmin == ||z - zq||^2
    }
}

// ---------------- reductions ----------------
__global__ __launch_bounds__(256)
void reduce1_kernel(const float* __restrict__ Spart, const unsigned int* __restrict__ bincnt,
                    const float* __restrict__ rowD,
                    double* __restrict__ te, double* __restrict__ tp, double* __restrict__ tm)
{
    const int k = blockIdx.x * 256 + threadIdx.x;   // grid 16 -> k < 4096
    double s = 0.0;
#pragma unroll 8
    for (int wg = 0; wg < 512; ++wg) s += (double)Spart[(size_t)wg * NCODES + k];
    const double avg = s * (1.0 / 65536.0);
    te[k] = avg * log(avg + 1e-10);
    const double ap = (double)bincnt[k] * (1.0 / 65536.0);
    tp[k] = ap * log(ap + 1e-10);
    double dm = 0.0;
#pragma unroll
    for (int j = 0; j < 16; ++j) dm += (double)rowD[k * 16 + j];
    tm[k] = dm;
}

__global__ __launch_bounds__(256)
void reduce2_kernel(const double* __restrict__ te, const double* __restrict__ tp,
                    const double* __restrict__ tm, float* __restrict__ out)
{
    __shared__ double sa[256], sb[256], sc[256];
    const int tid = threadIdx.x;
    double a = 0.0, b = 0.0, c = 0.0;
    for (int i = tid; i < NCODES; i += 256) { a += te[i]; b += tp[i]; c += tm[i]; }
    sa[tid] = a; sb[tid] = b; sc[tid] = c;
    __syncthreads();
    for (int s = 128; s > 0; s >>= 1) {
        if (tid < s) { sa[tid] += sa[tid + s]; sb[tid] += sb[tid + s]; sc[tid] += sc[tid + s]; }
        __syncthreads();
    }
    if (tid == 0) {
        const double entropy    = -sa[0];
        const double diversity  = log(4096.0) - entropy;
        const double perplexity = exp(-sb[0]);
        const double mse        = sc[0] * (1.0 / 16777216.0);
        const double vq         = 1.25 * mse + 0.1 * diversity;  // 0.25*c + e + 0.1*d, c==e
        out[16777216] = (float)vq;
        out[16777217] = (float)perplexity;
        out[16842754] = (float)diversity;
    }
}

extern "C" void kernel_launch(void* const* d_in, const int* in_sizes, int n_in,
                              void* d_out, int out_size, void* d_ws, size_t ws_size,
                              hipStream_t stream)
{
    const float* z   = (const float*)d_in[0];
    const float* emb = (const float*)d_in[1];
    float* out = (float*)d_out;
    char* ws = (char*)d_ws;
    if (ws_size < (size_t)WS_END) return;   // need ~17.4 MB scratch

    int*          cand_cnt = (int*)(ws + WS_CANDCNT);
    unsigned int* bincnt   = (unsigned int*)(ws + WS_BINCNT);
    float*        Spart    = (float*)(ws + WS_SPART);
    _Float16*     ef16     = (_Float16*)(ws + WS_EF16);
    float*        ee       = (float*)(ws + WS_EE);
    float*        rowD     = (float*)(ws + WS_ROWD);
    int*          cand_idx = (int*)(ws + WS_CANDIDX);
    double*       te       = (double*)(ws + WS_TE);
    double*       tp       = (double*)(ws + WS_TP);
    double*       tm       = (double*)(ws + WS_CANDIDX);  // cand_idx dead after refine

    hipMemsetAsync(d_ws, 0, WS_ZERO_END, stream);   // cand_cnt + bincnt (278 KB)
    hipLaunchKernelGGL(prep_kernel, dim3(NCODES / 4), dim3(256), 0, stream, emb, ef16, ee);
    hipLaunchKernelGGL(sweep_fused_kernel, dim3(NROWS / 128), dim3(256), 0, stream,
                       z, ef16, ee, Spart, cand_cnt, cand_idx);
    hipLaunchKernelGGL(refine_kernel, dim3(NROWS / 4), dim3(256), 0, stream,
                       z, emb, cand_cnt, cand_idx, out, out + 16777218, bincnt, rowD);
    hipLaunchKernelGGL(reduce1_kernel, dim3(16), dim3(256), 0, stream, Spart, bincnt, rowD, te, tp, tm);
    hipLaunchKernelGGL(reduce2_kernel, dim3(1), dim3(256), 0, stream, te, tp, tm, out);
}

// Round 6
// 541.042 us; speedup vs baseline: 1.0884x; 1.0884x over previous
//
#include <hip/hip_runtime.h>
#include <cstdint>
#include <cstddef>

// VQ-VAE vector quantizer forward, MI355X.
// B=65536 rows, K=4096 codes, D=256.
// Outputs (flat float32): z_q_st[B*D] | vq_loss | perplexity | indices[B] | diversity_loss

#define NROWS     65536
#define NCODES    4096
#define DDIM      256
#define CAND_CAP  24
#define MARGIN    2.0f
#define SKIP_THR  17.0f

typedef _Float16 half8 __attribute__((ext_vector_type(8)));
typedef _Float16 half4 __attribute__((ext_vector_type(4)));
typedef float    f32x4 __attribute__((ext_vector_type(4)));

// ---- workspace layout (bytes) ----
#define WS_CANDCNT  0u          // 65536*4   = 262144   (zeroed)
#define WS_BINCNT   262144u     // 4096*4    = 16384    (zeroed)
#define WS_ZERO_END 278528u
#define WS_SPART    278528u     // 512*4096*4 = 8388608 (fully written by sweep)
#define WS_EF16     8667136u    // 4096*256*2 = 2097152
#define WS_EE       10764288u   // 4096*4     = 16384
#define WS_ROWD     10780672u   // 65536*4    = 262144
#define WS_CANDIDX  11042816u   // 65536*24*4 = 6291456 (aliased as tm[4096] dbl after refine)
#define WS_TE       17334272u   // 4096*8     = 32768
#define WS_TP       17367040u   // 4096*8     = 32768
#define WS_END      17399808u

__device__ __forceinline__ void gload_lds16(const void* g, void* lds) {
    __builtin_amdgcn_global_load_lds(
        (const __attribute__((address_space(1))) unsigned int*)g,
        (__attribute__((address_space(3))) unsigned int*)lds, 16, 0, 0);
}

// ---------------- prep (embedding only): fp32 -> fp16 copy + row norms ----------------
__global__ __launch_bounds__(256)
void prep_kernel(const float* __restrict__ src, _Float16* __restrict__ dst,
                 float* __restrict__ norms)
{
    const int tid = threadIdx.x;
    const int w = tid >> 6, l = tid & 63;
    const int row = blockIdx.x * 4 + w;
    const float4 v = *(const float4*)(src + (size_t)row * DDIM + l * 4);
    half4 h;
    h[0] = (_Float16)v.x; h[1] = (_Float16)v.y;
    h[2] = (_Float16)v.z; h[3] = (_Float16)v.w;
    *(half4*)(dst + (size_t)row * DDIM + l * 4) = h;
    double s = (double)v.x * v.x + (double)v.y * v.y
             + (double)v.z * v.z + (double)v.w * v.w;
#pragma unroll
    for (int off = 1; off < 64; off <<= 1) s += __shfl_xor(s, off, 64);
    if (l == 0) norms[row] = (float)s;
}

// ---------------- fused two-phase distance sweep, double-buffered ----------------
// Block: 128 rows x all 4096 codes, 4 waves (wave w owns rows w*32..+31, all 64
// tile codes). A fragments (fp16, converted in-register) live in VGPRs throughout.
// B: 64-code x K=256 sub-tiles, 2 x 32 KB LDS double-buffer, stored FRAGMENT-MAJOR:
//   slot (ksl*4+cf)*1024 + lane*16  <-  global code cf*16+(l&15), kbytes ksl*64+(l>>4)*16
// staged via global_load_lds (linear LDS dest = lane*16; per-lane global source does
// the permute, rule #21). Reads are lane-linear ds_read_b128 with immediate offsets
// -> ZERO bank conflicts by construction. Operand values per (lane,instr) match the
// round-4 layout, so distances are bitwise-reproducible.
// Sweep runs on shifted distances d' = ||e||^2 - 2 z.e (row-shift invariant).
// Phase 0 (steps 0..63): exact online (m, Z), defer-rescale, skip-far exp.
// Phase 1 (steps 64..127): identical d'; soft partials into LDS Sl; candidates.
__global__ __launch_bounds__(256, 2)
void sweep_fused_kernel(const float* __restrict__ z, const _Float16* __restrict__ ef,
                        const float* __restrict__ ee, float* __restrict__ Spart,
                        int* __restrict__ cand_cnt, int* __restrict__ cand_idx)
{
    __shared__ _Float16 Bl[2][64 * 256];   // 2 x 32 KB, fragment-major
    __shared__ float Sl[NCODES];           // 16 KB soft accumulator

    const int tid = threadIdx.x;
    const int w = tid >> 6, l = tid & 63;
    const int lg = l >> 4, lc = l & 15;
    const int row0 = blockIdx.x * 128;

    // A fragments: row = row0 + w*32 + fr*16 + lc, k = ksl*32 + lg*8 .. +8 (f32 -> f16)
    half8 af[2][8];
#pragma unroll
    for (int fr = 0; fr < 2; ++fr)
#pragma unroll
    for (int ksl = 0; ksl < 8; ++ksl) {
        const float* zp = z + (size_t)(row0 + w * 32 + fr * 16 + lc) * DDIM + ksl * 32 + lg * 8;
        const float4 v0 = *(const float4*)zp;
        const float4 v1 = *(const float4*)(zp + 4);
        half8 h;
        h[0] = (_Float16)v0.x; h[1] = (_Float16)v0.y; h[2] = (_Float16)v0.z; h[3] = (_Float16)v0.w;
        h[4] = (_Float16)v1.x; h[5] = (_Float16)v1.y; h[6] = (_Float16)v1.z; h[7] = (_Float16)v1.w;
        af[fr][ksl] = h;
    }

    for (int i = tid; i < NCODES; i += 256) Sl[i] = 0.0f;

    // staging: instr it_g = w*8+it = slot index (ksl=it_g>>2, cf=it_g&3); lane l
    // fetches global code cf*16+lc at kbytes ksl*64+lg*16 -> LDS it_g*1024 + l*16.
    int soff[8];
#pragma unroll
    for (int it = 0; it < 8; ++it) {
        const int it_g = w * 8 + it;
        const int ksl = it_g >> 2, cf = it_g & 3;
        soff[it] = (cf * 16 + lc) * 512 + ksl * 64 + lg * 16;
    }
    const char* efb = (const char*)ef;
    char* blb = (char*)&Bl[0][0];

    float pm[8], pZ[8];
#pragma unroll
    for (int i = 0; i < 8; ++i) { pm[i] = 1e30f; pZ[i] = 0.0f; }

    // prologue: stage tile nt=0 into buffer 0
#pragma unroll
    for (int it = 0; it < 8; ++it)
        gload_lds16(efb + soff[it], blb + (w * 8 + it) * 1024);
    __syncthreads();

    for (int s = 0; s < 128; ++s) {
        const int cur = s & 1;
        const int nt = s & 63;

        if (s < 127) {                      // stage next sub-tile into other buffer
            const int nnt = (s + 1) & 63;
            const char* src = efb + ((size_t)nnt << 15);
            char* dst = blb + (cur ^ 1) * 32768;
#pragma unroll
            for (int it = 0; it < 8; ++it)
                gload_lds16(src + soff[it], dst + (w * 8 + it) * 1024);
        }

        float eev[4];
#pragma unroll
        for (int cf = 0; cf < 4; ++cf) eev[cf] = ee[nt * 64 + cf * 16 + lc];

        f32x4 acc[2][4];
#pragma unroll
        for (int fr = 0; fr < 2; ++fr)
#pragma unroll
            for (int cf = 0; cf < 4; ++cf) acc[fr][cf] = (f32x4){0.f, 0.f, 0.f, 0.f};

        // lane-linear B reads (conflict-free), immediate offsets
        const char* bb = blb + cur * 32768 + (l << 4);
#pragma unroll
        for (int ksl = 0; ksl < 8; ++ksl) {
#pragma unroll
            for (int cf = 0; cf < 4; ++cf) {
                const half8 b = *(const half8*)(bb + (ksl * 4 + cf) * 1024);
                acc[0][cf] = __builtin_amdgcn_mfma_f32_16x16x32_f16(af[0][ksl], b, acc[0][cf], 0, 0, 0);
                acc[1][cf] = __builtin_amdgcn_mfma_f32_16x16x32_f16(af[1][ksl], b, acc[1][cf], 0, 0, 0);
            }
        }

        if (s < 64) {
            // phase 0: exact online (m, Z); rescale only on min-improve; skip far groups
#pragma unroll
            for (int fr = 0; fr < 2; ++fr)
#pragma unroll
            for (int reg = 0; reg < 4; ++reg) {
                const int ri = fr * 4 + reg;
                const float d0 = fmaf(-2.0f, acc[fr][0][reg], eev[0]);
                const float d1 = fmaf(-2.0f, acc[fr][1][reg], eev[1]);
                const float d2 = fmaf(-2.0f, acc[fr][2][reg], eev[2]);
                const float d3 = fmaf(-2.0f, acc[fr][3][reg], eev[3]);
                const float mloc = fminf(fminf(d0, d1), fminf(d2, d3));
                float m = pm[ri];
                if (mloc < m + SKIP_THR) {   // dropped terms < e^-17, Z >= 1
                    if (mloc < m) { pZ[ri] *= __expf(mloc - m); m = mloc; pm[ri] = m; }
                    pZ[ri] += __expf(m - d0) + __expf(m - d1) + __expf(m - d2) + __expf(m - d3);
                }
            }
        } else {
            // phase 1: d' bitwise identical to phase 0 (same regs, same ops)
            float sp[4] = {0.f, 0.f, 0.f, 0.f};
#pragma unroll
            for (int fr = 0; fr < 2; ++fr)
#pragma unroll
            for (int reg = 0; reg < 4; ++reg) {
                const int ri = fr * 4 + reg;
                const float m = pm[ri], iz = pZ[ri];   // pZ holds 1/Z in phase 1
#pragma unroll
                for (int cf = 0; cf < 4; ++cf) {
                    const float d = fmaf(-2.0f, acc[fr][cf][reg], eev[cf]);
                    if (d <= m + SKIP_THR) {
                        sp[cf] += __expf(m - d) * iz;
                        if (d <= m + MARGIN) {   // m = exact min of phase-0 d' for this row
                            const int rg_ = row0 + w * 32 + fr * 16 + lg * 4 + reg;
                            const int slot = atomicAdd(&cand_cnt[rg_], 1);
                            if (slot < CAND_CAP)
                                cand_idx[(size_t)rg_ * CAND_CAP + slot] = nt * 64 + cf * 16 + lc;
                        }
                    }
                }
            }
#pragma unroll
            for (int cf = 0; cf < 4; ++cf) {   // sum across lg, then LDS accumulate
                float v = sp[cf];
                v += __shfl_xor(v, 16, 64);
                v += __shfl_xor(v, 32, 64);
                if (l < 16) atomicAdd(&Sl[nt * 64 + cf * 16 + l], v);
            }
        }

        if (s == 63) {
            // phase boundary: merge (m,Z) across the 16 lanes sharing each row; pZ := 1/Z
#pragma unroll
            for (int ri = 0; ri < 8; ++ri) {
                float m = pm[ri], Zv = pZ[ri];
#pragma unroll
                for (int off = 1; off < 16; off <<= 1) {
                    const float mo = __shfl_xor(m, off, 64);
                    const float Zo = __shfl_xor(Zv, off, 64);
                    const float mn = fminf(m, mo);
                    Zv = Zv * __expf(mn - m) + Zo * __expf(mn - mo);
                    m = mn;
                }
                pm[ri] = m;
                pZ[ri] = 1.0f / Zv;
            }
        }

        __syncthreads();   // drains stage(s+1) loads (issued a full compute phase ago)
    }

    for (int i = tid; i < NCODES; i += 256)
        Spart[(size_t)blockIdx.x * NCODES + i] = Sl[i];
}

// ---------------- refine: exact fp64 argmin over candidates ----------------
__global__ __launch_bounds__(256)
void refine_kernel(const float* __restrict__ z, const float* __restrict__ emb,
                   const int* __restrict__ cand_cnt, const int* __restrict__ cand_idx,
                   float* __restrict__ out_zq, float* __restrict__ out_idx,
                   unsigned int* __restrict__ bincnt, float* __restrict__ rowD)
{
    const int tid = threadIdx.x;
    const int w = tid >> 6, l = tid & 63;
    const int row = blockIdx.x * 4 + w;
    const float4 zv = *(const float4*)(z + (size_t)row * DDIM + l * 4);
    const double z0 = zv.x, z1 = zv.y, z2 = zv.z, z3 = zv.w;
    const int craw = cand_cnt[row];
    const int cnt = craw < 1 ? 1 : (craw > CAND_CAP ? CAND_CAP : craw);
    double dmin = 1e300; int kmin = 0;
    for (int c = 0; c < cnt; ++c) {
        int k = (craw < 1) ? 0 : cand_idx[(size_t)row * CAND_CAP + c];
        k &= (NCODES - 1);
        const float4 ev = *(const float4*)(emb + (size_t)k * DDIM + l * 4);
        const double t0 = z0 - ev.x, t1 = z1 - ev.y, t2 = z2 - ev.z, t3 = z3 - ev.w;
        double s = t0 * t0 + t1 * t1 + t2 * t2 + t3 * t3;
#pragma unroll
        for (int off = 1; off < 64; off <<= 1) s += __shfl_xor(s, off, 64);
        if (s < dmin || (s == dmin && k < kmin)) { dmin = s; kmin = k; }
    }
    const float4 bv = *(const float4*)(emb + (size_t)kmin * DDIM + l * 4);
    *(float4*)(out_zq + (size_t)row * DDIM + l * 4) = bv;   // z + sg(zq - z) == zq
    if (l == 0) {
        out_idx[row] = (float)kmin;
        atomicAdd(&bincnt[kmin], 1u);
        rowD[row] = (float)dmin;                             // dmin == ||z - zq||^2
    }
}

// ---------------- reductions ----------------
__global__ __launch_bounds__(256)
void reduce1_kernel(const float* __restrict__ Spart, const unsigned int* __restrict__ bincnt,
                    const float* __restrict__ rowD,
                    double* __restrict__ te, double* __restrict__ tp, double* __restrict__ tm)
{
    const int k = blockIdx.x * 256 + threadIdx.x;   // grid 16 -> k < 4096
    double s = 0.0;
#pragma unroll 8
    for (int wg = 0; wg < 512; ++wg) s += (double)Spart[(size_t)wg * NCODES + k];
    const double avg = s * (1.0 / 65536.0);
    te[k] = avg * log(avg + 1e-10);
    const double ap = (double)bincnt[k] * (1.0 / 65536.0);
    tp[k] = ap * log(ap + 1e-10);
    double dm = 0.0;
#pragma unroll
    for (int j = 0; j < 16; ++j) dm += (double)rowD[k * 16 + j];
    tm[k] = dm;
}

__global__ __launch_bounds__(256)
void reduce2_kernel(const double* __restrict__ te, const double* __restrict__ tp,
                    const double* __restrict__ tm, float* __restrict__ out)
{
    __shared__ double sa[256], sb[256], sc[256];
    const int tid = threadIdx.x;
    double a = 0.0, b = 0.0, c = 0.0;
    for (int i = tid; i < NCODES; i += 256) { a += te[i]; b += tp[i]; c += tm[i]; }
    sa[tid] = a; sb[tid] = b; sc[tid] = c;
    __syncthreads();
    for (int s = 128; s > 0; s >>= 1) {
        if (tid < s) { sa[tid] += sa[tid + s]; sb[tid] += sb[tid + s]; sc[tid] += sc[tid + s]; }
        __syncthreads();
    }
    if (tid == 0) {
        const double entropy    = -sa[0];
        const double diversity  = log(4096.0) - entropy;
        const double perplexity = exp(-sb[0]);
        const double mse        = sc[0] * (1.0 / 16777216.0);
        const double vq         = 1.25 * mse + 0.1 * diversity;  // 0.25*c + e + 0.1*d, c==e
        out[16777216] = (float)vq;
        out[16777217] = (float)perplexity;
        out[16842754] = (float)diversity;
    }
}

extern "C" void kernel_launch(void* const* d_in, const int* in_sizes, int n_in,
                              void* d_out, int out_size, void* d_ws, size_t ws_size,
                              hipStream_t stream)
{
    const float* z   = (const float*)d_in[0];
    const float* emb = (const float*)d_in[1];
    float* out = (float*)d_out;
    char* ws = (char*)d_ws;
    if (ws_size < (size_t)WS_END) return;   // need ~17.4 MB scratch

    int*          cand_cnt = (int*)(ws + WS_CANDCNT);
    unsigned int* bincnt   = (unsigned int*)(ws + WS_BINCNT);
    float*        Spart    = (float*)(ws + WS_SPART);
    _Float16*     ef16     = (_Float16*)(ws + WS_EF16);
    float*        ee       = (float*)(ws + WS_EE);
    float*        rowD     = (float*)(ws + WS_ROWD);
    int*          cand_idx = (int*)(ws + WS_CANDIDX);
    double*       te       = (double*)(ws + WS_TE);
    double*       tp       = (double*)(ws + WS_TP);
    double*       tm       = (double*)(ws + WS_CANDIDX);  // cand_idx dead after refine

    hipMemsetAsync(d_ws, 0, WS_ZERO_END, stream);   // cand_cnt + bincnt (278 KB)
    hipLaunchKernelGGL(prep_kernel, dim3(NCODES / 4), dim3(256), 0, stream, emb, ef16, ee);
    hipLaunchKernelGGL(sweep_fused_kernel, dim3(NROWS / 128), dim3(256), 0, stream,
                       z, ef16, ee, Spart, cand_cnt, cand_idx);
    hipLaunchKernelGGL(refine_kernel, dim3(NROWS / 4), dim3(256), 0, stream,
                       z, emb, cand_cnt, cand_idx, out, out + 16777218, bincnt, rowD);
    hipLaunchKernelGGL(reduce1_kernel, dim3(16), dim3(256), 0, stream, Spart, bincnt, rowD, te, tp, tm);
    hipLaunchKernelGGL(reduce2_kernel, dim3(1), dim3(256), 0, stream, te, tp, tm, out);
}

// Round 7
// 421.273 us; speedup vs baseline: 1.3979x; 1.2843x over previous
//
#include <hip/hip_runtime.h>
#include <cstdint>
#include <cstddef>

// VQ-VAE vector quantizer forward, MI355X.
// B=65536 rows, K=4096 codes, D=256.
// Outputs (flat float32): z_q_st[B*D] | vq_loss | perplexity | indices[B] | diversity_loss

#define NROWS     65536
#define NCODES    4096
#define DDIM      256
#define CAND_CAP  24
#define MARGIN    2.0f
#define SKIP_THR  17.0f

typedef _Float16 half8 __attribute__((ext_vector_type(8)));
typedef _Float16 half4 __attribute__((ext_vector_type(4)));
typedef float    f32x4 __attribute__((ext_vector_type(4)));

// ---- workspace layout (bytes) ----
#define WS_BINCNT   0u          // 4096*4    = 16384    (zeroed)
#define WS_ZERO_END 16384u
#define WS_CANDCNT  16384u      // 65536*4   = 262144   (plain-written by sweep, no zero)
#define WS_SPART    278528u     // 512*4096*4 = 8388608 (fully written by sweep)
#define WS_EF16     8667136u    // 4096*256*2 = 2097152
#define WS_EE       10764288u   // 4096*4     = 16384
#define WS_ROWD     10780672u   // 65536*4    = 262144
#define WS_CANDIDX  11042816u   // 65536*24*4 = 6291456 (aliased as tm[4096] dbl after refine)
#define WS_TE       17334272u   // 4096*8     = 32768
#define WS_TP       17367040u   // 4096*8     = 32768
#define WS_END      17399808u

__device__ __forceinline__ void gload_lds16(const void* g, void* lds) {
    __builtin_amdgcn_global_load_lds(
        (const __attribute__((address_space(1))) unsigned int*)g,
        (__attribute__((address_space(3))) unsigned int*)lds, 16, 0, 0);
}

// ---------------- prep (embedding only): fp32 -> fp16 copy + row norms ----------------
__global__ __launch_bounds__(256)
void prep_kernel(const float* __restrict__ src, _Float16* __restrict__ dst,
                 float* __restrict__ norms)
{
    const int tid = threadIdx.x;
    const int w = tid >> 6, l = tid & 63;
    const int row = blockIdx.x * 4 + w;
    const float4 v = *(const float4*)(src + (size_t)row * DDIM + l * 4);
    half4 h;
    h[0] = (_Float16)v.x; h[1] = (_Float16)v.y;
    h[2] = (_Float16)v.z; h[3] = (_Float16)v.w;
    *(half4*)(dst + (size_t)row * DDIM + l * 4) = h;
    double s = (double)v.x * v.x + (double)v.y * v.y
             + (double)v.z * v.z + (double)v.w * v.w;
#pragma unroll
    for (int off = 1; off < 64; off <<= 1) s += __shfl_xor(s, off, 64);
    if (l == 0) norms[row] = (float)s;
}

// ---------------- fused two-phase distance sweep, double-buffered ----------------
// Block: 128 rows x all 4096 codes, 4 waves (wave w owns rows w*32..+31, all 64
// tile codes). A fragments (fp16, converted in-register) live in VGPRs throughout.
// B: 64-code x K=256 sub-tiles, 2 x 32 KB LDS double-buffer, FRAGMENT-MAJOR layout
// (lane-linear ds_read_b128, zero bank conflicts; staged via global_load_lds with
// per-lane pre-permuted global source, rule #21).
// SCHEDULE (vmcnt discipline): per step, eev loads are issued BEFORE the 8 staging
// global_load_lds, so the epilogue's eev use waits only vmcnt(8) and the staging
// loads stay in flight until the pre-barrier drain (a full compute phase old).
// No mid-loop vmcnt(0). No vmem ops with return values anywhere in the loop:
// candidates use ballot + prefix-popcount slots + fire-and-forget stores.
// Sweep runs on shifted distances d' = ||e||^2 - 2 z.e (row-shift invariant).
// Phase 0 (steps 0..63): exact online (m, Z), defer-rescale, skip-far exp.
// Phase 1 (steps 64..127): identical d'; soft partials into LDS Sl; candidates.
__global__ __launch_bounds__(256, 2)
void sweep_fused_kernel(const float* __restrict__ z, const _Float16* __restrict__ ef,
                        const float* __restrict__ ee, float* __restrict__ Spart,
                        int* __restrict__ cand_cnt, int* __restrict__ cand_idx)
{
    __shared__ _Float16 Bl[2][64 * 256];   // 2 x 32 KB, fragment-major
    __shared__ float Sl[NCODES];           // 16 KB soft accumulator

    const int tid = threadIdx.x;
    const int w = tid >> 6, l = tid & 63;
    const int lg = l >> 4, lc = l & 15;
    const int row0 = blockIdx.x * 128;

    // A fragments: row = row0 + w*32 + fr*16 + lc, k = ksl*32 + lg*8 .. +8 (f32 -> f16)
    half8 af[2][8];
#pragma unroll
    for (int fr = 0; fr < 2; ++fr)
#pragma unroll
    for (int ksl = 0; ksl < 8; ++ksl) {
        const float* zp = z + (size_t)(row0 + w * 32 + fr * 16 + lc) * DDIM + ksl * 32 + lg * 8;
        const float4 v0 = *(const float4*)zp;
        const float4 v1 = *(const float4*)(zp + 4);
        half8 h;
        h[0] = (_Float16)v0.x; h[1] = (_Float16)v0.y; h[2] = (_Float16)v0.z; h[3] = (_Float16)v0.w;
        h[4] = (_Float16)v1.x; h[5] = (_Float16)v1.y; h[6] = (_Float16)v1.z; h[7] = (_Float16)v1.w;
        af[fr][ksl] = h;
    }

    for (int i = tid; i < NCODES; i += 256) Sl[i] = 0.0f;

    // staging: instr it_g = w*8+it = slot index (ksl=it_g>>2, cf=it_g&3); lane l
    // fetches global code cf*16+lc at kbytes ksl*64+lg*16 -> LDS it_g*1024 + l*16.
    int soff[8];
#pragma unroll
    for (int it = 0; it < 8; ++it) {
        const int it_g = w * 8 + it;
        const int ksl = it_g >> 2, cf = it_g & 3;
        soff[it] = (cf * 16 + lc) * 512 + ksl * 64 + lg * 16;
    }
    const char* efb = (const char*)ef;
    char* blb = (char*)&Bl[0][0];

    float pm[8], pZ[8];
#pragma unroll
    for (int i = 0; i < 8; ++i) { pm[i] = 1e30f; pZ[i] = 0.0f; }
    int bcnt[8];
#pragma unroll
    for (int i = 0; i < 8; ++i) bcnt[i] = 0;

    // prologue: stage tile nt=0 into buffer 0
#pragma unroll
    for (int it = 0; it < 8; ++it)
        gload_lds16(efb + soff[it], blb + (w * 8 + it) * 1024);
    __syncthreads();

    for (int s = 0; s < 128; ++s) {
        const int cur = s & 1;
        const int nt = s & 63;

        // eev for CURRENT tile: issued BEFORE staging so its wait is vmcnt(8),
        // leaving the staging loads in flight across the whole step.
        float eevc[4];
#pragma unroll
        for (int cf = 0; cf < 4; ++cf) eevc[cf] = ee[nt * 64 + cf * 16 + lc];

        if (s < 127) {                      // stage next sub-tile into other buffer
            const int nnt = (s + 1) & 63;
            const char* src = efb + ((size_t)nnt << 15);
            char* dst = blb + (cur ^ 1) * 32768;
#pragma unroll
            for (int it = 0; it < 8; ++it)
                gload_lds16(src + soff[it], dst + (w * 8 + it) * 1024);
        }

        f32x4 acc[2][4];
#pragma unroll
        for (int fr = 0; fr < 2; ++fr)
#pragma unroll
            for (int cf = 0; cf < 4; ++cf) acc[fr][cf] = (f32x4){0.f, 0.f, 0.f, 0.f};

        // lane-linear B reads (conflict-free), immediate offsets
        const char* bb = blb + cur * 32768 + (l << 4);
#pragma unroll
        for (int ksl = 0; ksl < 8; ++ksl) {
#pragma unroll
            for (int cf = 0; cf < 4; ++cf) {
                const half8 b = *(const half8*)(bb + (ksl * 4 + cf) * 1024);
                acc[0][cf] = __builtin_amdgcn_mfma_f32_16x16x32_f16(af[0][ksl], b, acc[0][cf], 0, 0, 0);
                acc[1][cf] = __builtin_amdgcn_mfma_f32_16x16x32_f16(af[1][ksl], b, acc[1][cf], 0, 0, 0);
            }
        }

        if (s < 64) {
            // phase 0: exact online (m, Z); rescale only on min-improve; skip far groups
#pragma unroll
            for (int fr = 0; fr < 2; ++fr)
#pragma unroll
            for (int reg = 0; reg < 4; ++reg) {
                const int ri = fr * 4 + reg;
                const float d0 = fmaf(-2.0f, acc[fr][0][reg], eevc[0]);
                const float d1 = fmaf(-2.0f, acc[fr][1][reg], eevc[1]);
                const float d2 = fmaf(-2.0f, acc[fr][2][reg], eevc[2]);
                const float d3 = fmaf(-2.0f, acc[fr][3][reg], eevc[3]);
                const float mloc = fminf(fminf(d0, d1), fminf(d2, d3));
                float m = pm[ri];
                if (mloc < m + SKIP_THR) {   // dropped terms < e^-17, Z >= 1
                    if (mloc < m) { pZ[ri] *= __expf(mloc - m); m = mloc; pm[ri] = m; }
                    pZ[ri] += __expf(m - d0) + __expf(m - d1) + __expf(m - d2) + __expf(m - d3);
                }
            }
        } else {
            // phase 1: d' bitwise identical to phase 0 (same regs, same ops)
            float sp[4] = {0.f, 0.f, 0.f, 0.f};
#pragma unroll
            for (int fr = 0; fr < 2; ++fr)
#pragma unroll
            for (int reg = 0; reg < 4; ++reg) {
                const int ri = fr * 4 + reg;
                const float m = pm[ri], iz = pZ[ri];   // pZ holds 1/Z in phase 1
#pragma unroll
                for (int cf = 0; cf < 4; ++cf) {
                    const float d = fmaf(-2.0f, acc[fr][cf][reg], eevc[cf]);
                    // candidates: ballot + prefix-popcount slots, no atomics,
                    // fire-and-forget stores. All 64 lanes participate in ballot.
                    const bool hit = (d <= m + MARGIN);  // m = exact phase-0 row min
                    const unsigned long long mk = __ballot(hit);
                    if (mk) {                            // uniform branch, rare
                        const unsigned grp = (unsigned)((mk >> (lg * 16)) & 0xFFFFull);
                        const int slot = bcnt[ri] + __popc(grp & ((1u << lc) - 1u));
                        if (hit && slot < CAND_CAP) {
                            const int rg_ = row0 + w * 32 + fr * 16 + lg * 4 + reg;
                            cand_idx[(size_t)rg_ * CAND_CAP + slot] = nt * 64 + cf * 16 + lc;
                        }
                        bcnt[ri] += __popc(grp);
                    }
                    if (d <= m + SKIP_THR) sp[cf] += __expf(m - d) * iz;
                }
            }
#pragma unroll
            for (int cf = 0; cf < 4; ++cf) {   // sum across lg, then LDS accumulate
                float v = sp[cf];
                v += __shfl_xor(v, 16, 64);
                v += __shfl_xor(v, 32, 64);
                if (l < 16) atomicAdd(&Sl[nt * 64 + cf * 16 + l], v);
            }
        }

        if (s == 63) {
            // phase boundary: merge (m,Z) across the 16 lanes sharing each row; pZ := 1/Z
#pragma unroll
            for (int ri = 0; ri < 8; ++ri) {
                float m = pm[ri], Zv = pZ[ri];
#pragma unroll
                for (int off = 1; off < 16; off <<= 1) {
                    const float mo = __shfl_xor(m, off, 64);
                    const float Zo = __shfl_xor(Zv, off, 64);
                    const float mn = fminf(m, mo);
                    Zv = Zv * __expf(mn - m) + Zo * __expf(mn - mo);
                    m = mn;
                }
                pm[ri] = m;
                pZ[ri] = 1.0f / Zv;
            }
        }

        __syncthreads();   // sole vmcnt drain: staging loads issued a full phase ago
    }

    // final: per-row candidate counts (plain stores; every row covered)
    if (lc == 0) {
#pragma unroll
        for (int fr = 0; fr < 2; ++fr)
#pragma unroll
        for (int reg = 0; reg < 4; ++reg)
            cand_cnt[row0 + w * 32 + fr * 16 + lg * 4 + reg] = bcnt[fr * 4 + reg];
    }

    for (int i = tid; i < NCODES; i += 256)
        Spart[(size_t)blockIdx.x * NCODES + i] = Sl[i];
}

// ---------------- refine: exact fp64 argmin over candidates ----------------
__global__ __launch_bounds__(256)
void refine_kernel(const float* __restrict__ z, const float* __restrict__ emb,
                   const int* __restrict__ cand_cnt, const int* __restrict__ cand_idx,
                   float* __restrict__ out_zq, float* __restrict__ out_idx,
                   unsigned int* __restrict__ bincnt, float* __restrict__ rowD)
{
    const int tid = threadIdx.x;
    const int w = tid >> 6, l = tid & 63;
    const int row = blockIdx.x * 4 + w;
    const float4 zv = *(const float4*)(z + (size_t)row * DDIM + l * 4);
    const double z0 = zv.x, z1 = zv.y, z2 = zv.z, z3 = zv.w;
    const int craw = cand_cnt[row];
    const int cnt = craw < 1 ? 1 : (craw > CAND_CAP ? CAND_CAP : craw);
    double dmin = 1e300; int kmin = 0;
    for (int c = 0; c < cnt; ++c) {
        int k = (craw < 1) ? 0 : cand_idx[(size_t)row * CAND_CAP + c];
        k &= (NCODES - 1);
        const float4 ev = *(const float4*)(emb + (size_t)k * DDIM + l * 4);
        const double t0 = z0 - ev.x, t1 = z1 - ev.y, t2 = z2 - ev.z, t3 = z3 - ev.w;
        double s = t0 * t0 + t1 * t1 + t2 * t2 + t3 * t3;
#pragma unroll
        for (int off = 1; off < 64; off <<= 1) s += __shfl_xor(s, off, 64);
        if (s < dmin || (s == dmin && k < kmin)) { dmin = s; kmin = k; }
    }
    const float4 bv = *(const float4*)(emb + (size_t)kmin * DDIM + l * 4);
    *(float4*)(out_zq + (size_t)row * DDIM + l * 4) = bv;   // z + sg(zq - z) == zq
    if (l == 0) {
        out_idx[row] = (float)kmin;
        atomicAdd(&bincnt[kmin], 1u);
        rowD[row] = (float)dmin;                             // dmin == ||z - zq||^2
    }
}

// ---------------- reductions ----------------
__global__ __launch_bounds__(256)
void reduce1_kernel(const float* __restrict__ Spart, const unsigned int* __restrict__ bincnt,
                    const float* __restrict__ rowD,
                    double* __restrict__ te, double* __restrict__ tp, double* __restrict__ tm)
{
    const int k = blockIdx.x * 256 + threadIdx.x;   // grid 16 -> k < 4096
    double s = 0.0;
#pragma unroll 8
    for (int wg = 0; wg < 512; ++wg) s += (double)Spart[(size_t)wg * NCODES + k];
    const double avg = s * (1.0 / 65536.0);
    te[k] = avg * log(avg + 1e-10);
    const double ap = (double)bincnt[k] * (1.0 / 65536.0);
    tp[k] = ap * log(ap + 1e-10);
    double dm = 0.0;
#pragma unroll
    for (int j = 0; j < 16; ++j) dm += (double)rowD[k * 16 + j];
    tm[k] = dm;
}

__global__ __launch_bounds__(256)
void reduce2_kernel(const double* __restrict__ te, const double* __restrict__ tp,
                    const double* __restrict__ tm, float* __restrict__ out)
{
    __shared__ double sa[256], sb[256], sc[256];
    const int tid = threadIdx.x;
    double a = 0.0, b = 0.0, c = 0.0;
    for (int i = tid; i < NCODES; i += 256) { a += te[i]; b += tp[i]; c += tm[i]; }
    sa[tid] = a; sb[tid] = b; sc[tid] = c;
    __syncthreads();
    for (int s = 128; s > 0; s >>= 1) {
        if (tid < s) { sa[tid] += sa[tid + s]; sb[tid] += sb[tid + s]; sc[tid] += sc[tid + s]; }
        __syncthreads();
    }
    if (tid == 0) {
        const double entropy    = -sa[0];
        const double diversity  = log(4096.0) - entropy;
        const double perplexity = exp(-sb[0]);
        const double mse        = sc[0] * (1.0 / 16777216.0);
        const double vq         = 1.25 * mse + 0.1 * diversity;  // 0.25*c + e + 0.1*d, c==e
        out[16777216] = (float)vq;
        out[16777217] = (float)perplexity;
        out[16842754] = (float)diversity;
    }
}

extern "C" void kernel_launch(void* const* d_in, const int* in_sizes, int n_in,
                              void* d_out, int out_size, void* d_ws, size_t ws_size,
                              hipStream_t stream)
{
    const float* z   = (const float*)d_in[0];
    const float* emb = (const float*)d_in[1];
    float* out = (float*)d_out;
    char* ws = (char*)d_ws;
    if (ws_size < (size_t)WS_END) return;   // need ~17.4 MB scratch

    unsigned int* bincnt   = (unsigned int*)(ws + WS_BINCNT);
    int*          cand_cnt = (int*)(ws + WS_CANDCNT);
    float*        Spart    = (float*)(ws + WS_SPART);
    _Float16*     ef16     = (_Float16*)(ws + WS_EF16);
    float*        ee       = (float*)(ws + WS_EE);
    float*        rowD     = (float*)(ws + WS_ROWD);
    int*          cand_idx = (int*)(ws + WS_CANDIDX);
    double*       te       = (double*)(ws + WS_TE);
    double*       tp       = (double*)(ws + WS_TP);
    double*       tm       = (double*)(ws + WS_CANDIDX);  // cand_idx dead after refine

    hipMemsetAsync(d_ws, 0, WS_ZERO_END, stream);   // bincnt only (16 KB)
    hipLaunchKernelGGL(prep_kernel, dim3(NCODES / 4), dim3(256), 0, stream, emb, ef16, ee);
    hipLaunchKernelGGL(sweep_fused_kernel, dim3(NROWS / 128), dim3(256), 0, stream,
                       z, ef16, ee, Spart, cand_cnt, cand_idx);
    hipLaunchKernelGGL(refine_kernel, dim3(NROWS / 4), dim3(256), 0, stream,
                       z, emb, cand_cnt, cand_idx, out, out + 16777218, bincnt, rowD);
    hipLaunchKernelGGL(reduce1_kernel, dim3(16), dim3(256), 0, stream, Spart, bincnt, rowD, te, tp, tm);
    hipLaunchKernelGGL(reduce2_kernel, dim3(1), dim3(256), 0, stream, te, tp, tm, out);
}